// Round 18
// baseline (128.148 us; speedup 1.0000x reference)
//
#include <hip/hip_runtime.h>

#define NN 30000
#define NE 120000
#define TPB 256
#define SB 118   // ceil(NN/256)
#define NT 1875  // node tiles of 16 (NN/16 exact)

typedef __attribute__((ext_vector_type(8))) __bf16 bf16x8;
typedef __attribute__((ext_vector_type(4))) float f32x4;

union B8 { bf16x8 b; unsigned short u[8]; uint4 q; };

__device__ __forceinline__ float blo(unsigned u) { return __uint_as_float(u << 16); }
__device__ __forceinline__ float bhi(unsigned u) { return __uint_as_float(u & 0xffff0000u); }

__device__ __forceinline__ unsigned short f2b(float f) {
  unsigned u = __float_as_uint(f);
  return (unsigned short)((u + 0x7fff + ((u >> 16) & 1)) >> 16);  // RNE
}

// ---------- MFMA B-fragment weight packing (R12-proven) ----------
__device__ __forceinline__ void pack_wb(int f, const float* kw2, const float* kb2,
                                        const float* root, uint4* Wb) {
  int ct = f >> 6, l = f & 63;
  int j = ct * 16 + (l & 15);
  int k = j >> 5, o = j & 31;
  int i0 = (l >> 4) * 8;
  B8 w;
#pragma unroll
  for (int ii = 0; ii < 8; ii++) {
    int i = i0 + ii;
    float v;
    if (k < 8) v = kw2[k * 1024 + i * 32 + o];
    else if (k == 8) v = kb2[i * 32 + o];
    else v = root[i * 32 + o];
    w.u[ii] = f2b(v);
  }
  Wb[f] = w.q;
}

__global__ void k_init(int* __restrict__ cnt_d, int* __restrict__ cnt_s,
                       int* __restrict__ gtot, const float* __restrict__ kw2,
                       const float* __restrict__ kb2, const float* __restrict__ root,
                       uint4* __restrict__ Wb) {
  int bid = blockIdx.x;
  if (bid < SB) {
    int n = bid * TPB + threadIdx.x;
    if (n < NN) { cnt_d[n] = 0; cnt_s[n] = 0; }
    if (bid == 0 && threadIdx.x < 2) gtot[threadIdx.x] = 0;
  } else {
    int f = (bid - SB) * TPB + threadIdx.x;
    if (f < 1280) pack_wb(f, kw2, kb2, root, Wb);
  }
}

// degree counts only (ck computed later in k_scatter)
__global__ void k_prep(const int* __restrict__ src, const int* __restrict__ dst,
                       int* __restrict__ cnt_d, int* __restrict__ cnt_s) {
  int e = blockIdx.x * TPB + threadIdx.x;
  if (e >= NE) return;
  atomicAdd(&cnt_d[dst[e]], 1);
  atomicAdd(&cnt_s[src[e]], 1);
}

// both CSR range allocations (inter-node order irrelevant) + icnt
__global__ void k_alloc(const int* __restrict__ cnt_d, const int* __restrict__ cnt_s,
                        int* __restrict__ gtot, int* __restrict__ rs_d,
                        int* __restrict__ wpos_d, int* __restrict__ rs_s,
                        int* __restrict__ wpos_s, float* __restrict__ icnt) {
  int n = blockIdx.x * TPB + threadIdx.x;
  if (n >= NN) return;
  int cd = cnt_d[n];
  int r = atomicAdd(&gtot[0], cd);
  rs_d[n] = r; wpos_d[n] = r;
  icnt[n] = 1.f / (float)max(cd, 1);
  int cs = cnt_s[n];
  int r2 = atomicAdd(&gtot[1], cs);
  rs_s[n] = r2; wpos_s[n] = r2;
}

// edge MLP + scatter into src-sorted payload: kce[ps], dpos[ps] = dst-sorted slot
__global__ void k_scatter(const int* __restrict__ src, const int* __restrict__ dst,
                          const float* __restrict__ ea, const float* __restrict__ w1,
                          const float* __restrict__ b1, int* __restrict__ wpos_s,
                          int* __restrict__ wpos_d, float* __restrict__ kce,
                          int* __restrict__ dpos) {
  int e = blockIdx.x * TPB + threadIdx.x;
  if (e >= NE) return;
  float a[6];
#pragma unroll
  for (int i = 0; i < 6; i++) a[i] = ea[e * 6 + i];
  float ck[8];
#pragma unroll
  for (int k = 0; k < 8; k++) {
    float s = b1[k];
#pragma unroll
    for (int i = 0; i < 6; i++) s = fmaf(a[i], w1[i * 8 + k], s);
    ck[k] = fmaxf(s, 0.f);
  }
  int ps = atomicAdd(&wpos_s[src[e]], 1);
  int pd = atomicAdd(&wpos_d[dst[e]], 1);
  float4 a4 = {ck[0], ck[1], ck[2], ck[3]};
  float4 b4 = {ck[4], ck[5], ck[6], ck[7]};
  *(float4*)&kce[(size_t)ps * 8] = a4;
  *(float4*)&kce[(size_t)ps * 8 + 4] = b4;
  dpos[ps] = pd;
}

// ---------- tile transform: hL(16x32) -> MFMA -> PL (LDS, stride 161) + Pr ----------
__device__ __forceinline__ void transform_tile(const float* hL, const uint4* Wb,
                                               unsigned* PL, float* Pr, int nb,
                                               int tid) {
  const int w = tid >> 6, lane = tid & 63;
  B8 Bf0, Bf1, Bf2, Bf3, Bf4;
  Bf0.q = Wb[(4 * w + 0) * 64 + lane];
  Bf1.q = Wb[(4 * w + 1) * 64 + lane];
  Bf2.q = Wb[(4 * w + 2) * 64 + lane];
  Bf3.q = Wb[(4 * w + 3) * 64 + lane];
  Bf4.q = Wb[(16 + w) * 64 + lane];
  const int row = lane & 15, k0 = (lane >> 4) * 8;
  B8 af;
#pragma unroll
  for (int ii = 0; ii < 8; ii++) af.u[ii] = f2b(hL[row * 32 + k0 + ii]);
  f32x4 z = {0.f, 0.f, 0.f, 0.f};
  f32x4 d0 = __builtin_amdgcn_mfma_f32_16x16x32_bf16(af.b, Bf0.b, z, 0, 0, 0);
  f32x4 d1 = __builtin_amdgcn_mfma_f32_16x16x32_bf16(af.b, Bf1.b, z, 0, 0, 0);
  f32x4 d2 = __builtin_amdgcn_mfma_f32_16x16x32_bf16(af.b, Bf2.b, z, 0, 0, 0);
  f32x4 d3 = __builtin_amdgcn_mfma_f32_16x16x32_bf16(af.b, Bf3.b, z, 0, 0, 0);
  f32x4 d4 = __builtin_amdgcn_mfma_f32_16x16x32_bf16(af.b, Bf4.b, z, 0, 0, 0);
  const int oo = lane & 15, r0 = (lane >> 4) * 4;
#pragma unroll
  for (int r = 0; r < 4; r++) {
    int nl = r0 + r;
    PL[nl * 161 + w * 32 + oo] = f2b(d0[r]) | ((unsigned)f2b(d2[r]) << 16);
    PL[nl * 161 + w * 32 + 16 + oo] = f2b(d1[r]) | ((unsigned)f2b(d3[r]) << 16);
    if (w == 0) PL[nl * 161 + 128 + oo] = f2b(d4[r]);
    else if (w == 1) PL[nl * 161 + 128 + 16 + oo] = f2b(d4[r]);
    else if (w == 2) Pr[(size_t)(nb + nl) * 32 + oo] = d4[r];
    else Pr[(size_t)(nb + nl) * 32 + 16 + oo] = d4[r];
  }
}

// ---------- out-messages: 16-lane group per src, P row from LDS ----------
__device__ __forceinline__ void out_msgs(const unsigned* PL, const int* __restrict__ rs_s,
                                         const int* __restrict__ cnt_s,
                                         const float* __restrict__ kce,
                                         const int* __restrict__ dpos,
                                         float* __restrict__ msg, int nb, int tid) {
  const int gid = tid >> 4, o16 = tid & 15;
  const int s = nb + gid;
  const unsigned* R = PL + gid * 161;
  unsigned q0 = R[o16],       q1 = R[16 + o16];
  unsigned q2 = R[32 + o16],  q3 = R[48 + o16];
  unsigned q4 = R[64 + o16],  q5 = R[80 + o16];
  unsigned q6 = R[96 + o16],  q7 = R[112 + o16];
  unsigned q8 = R[128 + o16], q9 = R[144 + o16];
  int rs = rs_s[s], re = rs + cnt_s[s];
  for (int j = rs; j < re; ++j) {
    float ckv = (o16 < 8) ? kce[(size_t)j * 8 + o16] : 0.f;
    int pd = dpos[j];
    float c0 = __shfl(ckv, 0, 16), c1 = __shfl(ckv, 1, 16);
    float c2 = __shfl(ckv, 2, 16), c3 = __shfl(ckv, 3, 16);
    float c4 = __shfl(ckv, 4, 16), c5 = __shfl(ckv, 5, 16);
    float c6 = __shfl(ckv, 6, 16), c7 = __shfl(ckv, 7, 16);
    float m0 = blo(q8), m1 = blo(q9);  // bias row, coefficient 1
    m0 = fmaf(c0, blo(q0), m0); m1 = fmaf(c0, blo(q1), m1);
    m0 = fmaf(c1, bhi(q0), m0); m1 = fmaf(c1, bhi(q1), m1);
    m0 = fmaf(c2, blo(q2), m0); m1 = fmaf(c2, blo(q3), m1);
    m0 = fmaf(c3, bhi(q2), m0); m1 = fmaf(c3, bhi(q3), m1);
    m0 = fmaf(c4, blo(q4), m0); m1 = fmaf(c4, blo(q5), m1);
    m0 = fmaf(c5, bhi(q4), m0); m1 = fmaf(c5, bhi(q5), m1);
    m0 = fmaf(c6, blo(q6), m0); m1 = fmaf(c6, blo(q7), m1);
    m0 = fmaf(c7, bhi(q6), m0); m1 = fmaf(c7, bhi(q7), m1);
    msg[(size_t)pd * 32 + o16] = m0;
    msg[(size_t)pd * 32 + 16 + o16] = m1;
  }
}

__device__ __forceinline__ float gather_node(int rs, int re, int half, int o,
                                             const float* __restrict__ msg) {
  float acc = 0.f;
  for (int j = rs + half; j < re; j += 2) acc += msg[(size_t)j * 32 + o];
  acc += __shfl_xor(acc, 32, 64);
  return acc;
}

// ---------- first layer: h0 = fc1(x) -> transform -> out-msgs ----------
__global__ __launch_bounds__(TPB, 4) void k_first(
    const float* __restrict__ x, const float* __restrict__ fc1w,
    const float* __restrict__ fc1b, const uint4* __restrict__ Wb,
    float* __restrict__ Pr, const int* __restrict__ rs_s,
    const int* __restrict__ cnt_s, const float* __restrict__ kce,
    const int* __restrict__ dpos, float* __restrict__ msgo) {
  __shared__ unsigned PL[16 * 161];
  __shared__ float hL[512];
  const int tid = threadIdx.x;
  const int nb = blockIdx.x * 16;
  for (int e2 = tid; e2 < 512; e2 += TPB) {
    int ln = e2 >> 5, oo = e2 & 31;
    hL[e2] = fmaf(x[nb + ln], fc1w[oo], fc1b[oo]);
  }
  __syncthreads();
  transform_tile(hL, Wb, PL, Pr, nb, tid);
  __syncthreads();
  out_msgs(PL, rs_s, cnt_s, kce, dpos, msgo, nb, tid);
}

// ---------- mid layer: msg-gather -> h -> transform -> out-msgs ----------
__global__ __launch_bounds__(TPB, 4) void k_layer(
    const int* __restrict__ rs_d, const int* __restrict__ cnt_d,
    const float* __restrict__ icnt, const float* __restrict__ msgi,
    float* __restrict__ Pr, const float* __restrict__ cbias,
    const uint4* __restrict__ Wb, const int* __restrict__ rs_s,
    const int* __restrict__ cnt_s, const float* __restrict__ kce,
    const int* __restrict__ dpos, float* __restrict__ msgo) {
  __shared__ unsigned PL[16 * 161];
  __shared__ float hL[512];
  const int tid = threadIdx.x, w = tid >> 6, lane = tid & 63;
  const int nb = blockIdx.x * 16;
  const int half = lane >> 5, o = lane & 31;
#pragma unroll 1
  for (int q = 0; q < 4; ++q) {
    int n = nb + 4 * w + q;
    int rs = rs_d[n], re = rs + cnt_d[n];
    float acc = gather_node(rs, re, half, o, msgi);
    if (lane < 32)
      hL[(4 * w + q) * 32 + o] =
          fmaxf(fmaf(acc, icnt[n], Pr[(size_t)n * 32 + o] + cbias[o]), 0.f);
  }
  __syncthreads();
  transform_tile(hL, Wb, PL, Pr, nb, tid);
  __syncthreads();
  out_msgs(PL, rs_s, cnt_s, kce, dpos, msgo, nb, tid);
}

// ---------- last: msg-gather -> h -> fc2 -> out ----------
__global__ void k_last(const int* __restrict__ rs_d, const int* __restrict__ cnt_d,
                       const float* __restrict__ icnt, const float* __restrict__ msgi,
                       const float* __restrict__ Pr, const float* __restrict__ cbias,
                       const float* __restrict__ fc2w, const float* __restrict__ fc2b,
                       float* __restrict__ out) {
  const int tid = threadIdx.x, w = tid >> 6, lane = tid & 63;
  const int nb = blockIdx.x * 16;
  const int half = lane >> 5, o = lane & 31;
#pragma unroll 1
  for (int q = 0; q < 4; ++q) {
    int n = nb + 4 * w + q;
    int rs = rs_d[n], re = rs + cnt_d[n];
    float acc = gather_node(rs, re, half, o, msgi);
    if (lane < 32) {
      float hv = fmaxf(fmaf(acc, icnt[n], Pr[(size_t)n * 32 + o] + cbias[o]), 0.f);
      float s2 = hv * fc2w[o];
#pragma unroll
      for (int d = 16; d; d >>= 1) s2 += __shfl_xor(s2, d, 32);
      if (o == 0) out[n] = s2 + fc2b[0];
    }
  }
}

extern "C" void kernel_launch(void* const* d_in, const int* in_sizes, int n_in,
                              void* d_out, int out_size, void* d_ws, size_t ws_size,
                              hipStream_t stream) {
  const float* x     = (const float*)d_in[0];
  const int*   ei    = (const int*)d_in[1];
  const float* ea    = (const float*)d_in[2];
  const float* fc1w  = (const float*)d_in[3];
  const float* fc1b  = (const float*)d_in[4];
  const float* kw1   = (const float*)d_in[5];
  const float* kb1   = (const float*)d_in[6];
  const float* kw2   = (const float*)d_in[7];
  const float* kb2   = (const float*)d_in[8];
  const float* root  = (const float*)d_in[9];
  const float* cbias = (const float*)d_in[10];
  const float* fc2w  = (const float*)d_in[11];
  const float* fc2b  = (const float*)d_in[12];
  float* out = (float*)d_out;
  const int* srcp = ei;
  const int* dstp = ei + NE;

  float* ws = (float*)d_ws;
  float* kce    = ws;                          // NE*8
  int*   dpos   = (int*)(kce + NE * 8);        // NE
  int*   cnt_d  = dpos + NE;                   // NN
  int*   cnt_s  = cnt_d + NN;                  // NN
  int*   rs_d   = cnt_s + NN;                  // NN
  int*   rs_s   = rs_d + NN;                   // NN
  int*   wpos_d = rs_s + NN;                   // NN
  int*   wpos_s = wpos_d + NN;                 // NN
  int*   gtot   = wpos_s + NN;                 // 2 (+pad 128)
  float* icnt   = (float*)(gtot + 128);        // NN
  float* Pr     = icnt + NN;                   // NN*32
  uint4* Wb     = (uint4*)(Pr + (size_t)NN * 32);  // 1280 uint4
  float* msg0   = (float*)(Wb + 1280);         // NE*32
  float* msg1   = msg0 + (size_t)NE * 32;      // NE*32

  k_init<<<SB + 5, TPB, 0, stream>>>(cnt_d, cnt_s, gtot, kw2, kb2, root, Wb);
  k_prep<<<(NE + TPB - 1) / TPB, TPB, 0, stream>>>(srcp, dstp, cnt_d, cnt_s);
  k_alloc<<<SB, TPB, 0, stream>>>(cnt_d, cnt_s, gtot, rs_d, wpos_d, rs_s, wpos_s, icnt);
  k_scatter<<<(NE + TPB - 1) / TPB, TPB, 0, stream>>>(srcp, dstp, ea, kw1, kb1,
                                                      wpos_s, wpos_d, kce, dpos);

  k_first<<<NT, TPB, 0, stream>>>(x, fc1w, fc1b, Wb, Pr, rs_s, cnt_s, kce, dpos, msg0);
  k_layer<<<NT, TPB, 0, stream>>>(rs_d, cnt_d, icnt, msg0, Pr, cbias, Wb,
                                  rs_s, cnt_s, kce, dpos, msg1);
  k_layer<<<NT, TPB, 0, stream>>>(rs_d, cnt_d, icnt, msg1, Pr, cbias, Wb,
                                  rs_s, cnt_s, kce, dpos, msg0);
  k_layer<<<NT, TPB, 0, stream>>>(rs_d, cnt_d, icnt, msg0, Pr, cbias, Wb,
                                  rs_s, cnt_s, kce, dpos, msg1);
  k_last<<<NT, TPB, 0, stream>>>(rs_d, cnt_d, icnt, msg1, Pr, cbias, fc2w, fc2b, out);
}

// Round 19
// 113.595 us; speedup vs baseline: 1.1281x; 1.1281x over previous
//
#include <hip/hip_runtime.h>

#define NN 30000
#define NE 120000
#define TPB 256
#define SB 118   // ceil(NN/256)
#define NW 1875  // NN/16 exact
#define NB1 469  // ceil(NW*64/256) blocks for node1 part

typedef __attribute__((ext_vector_type(8))) __bf16 bf16x8;
typedef __attribute__((ext_vector_type(4))) float f32x4;

union B8 { bf16x8 b; unsigned short u[8]; uint4 q; };

__device__ __forceinline__ float blo(unsigned u) { return __uint_as_float(u << 16); }
__device__ __forceinline__ float bhi(unsigned u) { return __uint_as_float(u & 0xffff0000u); }

__device__ __forceinline__ unsigned short f2b(float f) {
  unsigned u = __float_as_uint(f);
  return (unsigned short)((u + 0x7fff + ((u >> 16) & 1)) >> 16);  // RNE
}

// ---------- weight fragment packing ----------
__device__ __forceinline__ void pack_wb(int f, const float* kw2, const float* kb2,
                                        const float* root, uint4* Wb) {
  int ct = f >> 6, l = f & 63;
  int j = ct * 16 + (l & 15);
  int k = j >> 5, o = j & 31;
  int i0 = (l >> 4) * 8;
  B8 w;
#pragma unroll
  for (int ii = 0; ii < 8; ii++) {
    int i = i0 + ii;
    float v;
    if (k < 8) v = kw2[k * 1024 + i * 32 + o];
    else if (k == 8) v = kb2[i * 32 + o];
    else v = root[i * 32 + o];
    w.u[ii] = f2b(v);
  }
  Wb[f] = w.q;
}

__global__ void k_init(int* __restrict__ cnt, int* __restrict__ gtotal,
                       const float* __restrict__ kw2, const float* __restrict__ kb2,
                       const float* __restrict__ root, uint4* __restrict__ Wb) {
  int bid = blockIdx.x;
  if (bid < SB) {
    int n = bid * TPB + threadIdx.x;
    if (n < NN) cnt[n] = 0;
    if (bid == 0 && threadIdx.x == 0) *gtotal = 0;
  } else {
    int f = (bid - SB) * TPB + threadIdx.x;
    if (f < 1280) pack_wb(f, kw2, kb2, root, Wb);
  }
}

__global__ void k_prep(const float* __restrict__ ea, const float* __restrict__ w1,
                       const float* __restrict__ b1, const int* __restrict__ dst,
                       float* __restrict__ kc, int* __restrict__ cnt) {
  int e = blockIdx.x * TPB + threadIdx.x;
  if (e >= NE) return;
  float a[6];
#pragma unroll
  for (int i = 0; i < 6; i++) a[i] = ea[e * 6 + i];
#pragma unroll
  for (int k = 0; k < 8; k++) {
    float s = b1[k];
#pragma unroll
    for (int i = 0; i < 6; i++) s = fmaf(a[i], w1[i * 8 + k], s);
    kc[e * 8 + k] = fmaxf(s, 0.f);
  }
  atomicAdd(&cnt[dst[e]], 1);
}

// CSR range allocation without prefix scan (inter-node order irrelevant)
__global__ void k_alloc(const int* __restrict__ cnt, int* __restrict__ gtotal,
                        int* __restrict__ rowstart, int* __restrict__ wpos,
                        float* __restrict__ icnt) {
  int n = blockIdx.x * TPB + threadIdx.x;
  if (n >= NN) return;
  int c = cnt[n];
  int r = atomicAdd(gtotal, c);
  rowstart[n] = r;
  wpos[n] = r;
  icnt[n] = 1.f / (float)max(c, 1);
}

// fused: blocks [0,NB1) = first MFMA transform (h0=fc1(x)); blocks [NB1,..) = scatter
__global__ __launch_bounds__(TPB, 4) void k_scatnode(
    const int* __restrict__ dst, const int* __restrict__ src,
    const float* __restrict__ kc, int* __restrict__ wpos, int* __restrict__ srcs,
    float* __restrict__ kcs, const float* __restrict__ x,
    const float* __restrict__ fc1w, const float* __restrict__ fc1b,
    const uint4* __restrict__ Wb, unsigned* __restrict__ Pb, float* __restrict__ Pr) {
  if (blockIdx.x < NB1) {
    const int l = threadIdx.x & 63;
    const int wid = blockIdx.x * (TPB / 64) + (threadIdx.x >> 6);
    if (wid >= NW) return;
    const int nb = wid * 16;
    B8 Bf[20];
#pragma unroll
    for (int ct = 0; ct < 20; ct++) Bf[ct].q = Wb[ct * 64 + l];
    const int row = nb + (l & 15);
    const int k0 = (l >> 4) * 8;
    B8 af;
    float xv = x[row];
#pragma unroll
    for (int ii = 0; ii < 8; ii++)
      af.u[ii] = f2b(fmaf(xv, fc1w[k0 + ii], fc1b[k0 + ii]));
    const int oo = l & 15;
    const int r0 = (l >> 4) * 4;
#pragma unroll
    for (int kp = 0; kp < 4; kp++) {
      f32x4 d0 = {0.f, 0.f, 0.f, 0.f}, d1 = d0, d2 = d0, d3 = d0;
      d0 = __builtin_amdgcn_mfma_f32_16x16x32_bf16(af.b, Bf[4 * kp + 0].b, d0, 0, 0, 0);
      d1 = __builtin_amdgcn_mfma_f32_16x16x32_bf16(af.b, Bf[4 * kp + 1].b, d1, 0, 0, 0);
      d2 = __builtin_amdgcn_mfma_f32_16x16x32_bf16(af.b, Bf[4 * kp + 2].b, d2, 0, 0, 0);
      d3 = __builtin_amdgcn_mfma_f32_16x16x32_bf16(af.b, Bf[4 * kp + 3].b, d3, 0, 0, 0);
#pragma unroll
      for (int r = 0; r < 4; r++) {
        int n = nb + r0 + r;
        Pb[(size_t)n * 160 + kp * 32 + oo] = f2b(d0[r]) | ((unsigned)f2b(d2[r]) << 16);
        Pb[(size_t)n * 160 + kp * 32 + 16 + oo] = f2b(d1[r]) | ((unsigned)f2b(d3[r]) << 16);
      }
    }
    {
      f32x4 d0 = {0.f, 0.f, 0.f, 0.f}, d1 = d0, d2 = d0, d3 = d0;
      d0 = __builtin_amdgcn_mfma_f32_16x16x32_bf16(af.b, Bf[16].b, d0, 0, 0, 0);
      d1 = __builtin_amdgcn_mfma_f32_16x16x32_bf16(af.b, Bf[17].b, d1, 0, 0, 0);
      d2 = __builtin_amdgcn_mfma_f32_16x16x32_bf16(af.b, Bf[18].b, d2, 0, 0, 0);
      d3 = __builtin_amdgcn_mfma_f32_16x16x32_bf16(af.b, Bf[19].b, d3, 0, 0, 0);
#pragma unroll
      for (int r = 0; r < 4; r++) {
        int n = nb + r0 + r;
        Pb[(size_t)n * 160 + 128 + oo] = f2b(d0[r]);
        Pb[(size_t)n * 160 + 128 + 16 + oo] = f2b(d1[r]);
        Pr[(size_t)n * 32 + oo] = d2[r];
        Pr[(size_t)n * 32 + 16 + oo] = d3[r];
      }
    }
  } else {
    int e = (blockIdx.x - NB1) * TPB + threadIdx.x;
    if (e >= NE) return;
    int pos = atomicAdd(&wpos[dst[e]], 1);
    srcs[pos] = src[e];
    float4 a = *(const float4*)&kc[e * 8];
    float4 b = *(const float4*)&kc[e * 8 + 4];
    *(float4*)&kcs[(size_t)pos * 8] = a;
    *(float4*)&kcs[(size_t)pos * 8 + 4] = b;
  }
}

// 4-edges-in-flight gather for one node; lane = eq*16+o16; returns acc for
// outputs o16 (acc0) and o16+16 (acc1), valid in all lanes after xor-merge.
__device__ __forceinline__ void gather4(
    int rs, int re, int eq, int o16, const int* __restrict__ srcs,
    const float* __restrict__ kcs, const unsigned* __restrict__ Pb,
    float& acc0, float& acc1) {
  acc0 = 0.f; acc1 = 0.f;
  for (int j0 = rs; j0 < re; j0 += 4) {
    int j = j0 + eq;
    bool valid = (j < re);
    int jj = valid ? j : rs;
    int s = srcs[jj];
    float ckv = (o16 < 8) ? kcs[(size_t)jj * 8 + o16] : 0.f;
    const unsigned* Ps = Pb + (size_t)s * 160;
    unsigned pa0 = Ps[o16],       pa1 = Ps[16 + o16];
    unsigned pb0 = Ps[32 + o16],  pb1 = Ps[48 + o16];
    unsigned pc0 = Ps[64 + o16],  pc1 = Ps[80 + o16];
    unsigned pd0 = Ps[96 + o16],  pd1 = Ps[112 + o16];
    unsigned pe0 = Ps[128 + o16], pe1 = Ps[144 + o16];
    float m0 = blo(pe0), m1 = blo(pe1);  // bias row, coefficient 1
    float c0 = __shfl(ckv, 0, 16), c1 = __shfl(ckv, 1, 16);
    float c2 = __shfl(ckv, 2, 16), c3 = __shfl(ckv, 3, 16);
    float c4 = __shfl(ckv, 4, 16), c5 = __shfl(ckv, 5, 16);
    float c6 = __shfl(ckv, 6, 16), c7 = __shfl(ckv, 7, 16);
    m0 = fmaf(c0, blo(pa0), m0); m1 = fmaf(c0, blo(pa1), m1);
    m0 = fmaf(c1, bhi(pa0), m0); m1 = fmaf(c1, bhi(pa1), m1);
    m0 = fmaf(c2, blo(pb0), m0); m1 = fmaf(c2, blo(pb1), m1);
    m0 = fmaf(c3, bhi(pb0), m0); m1 = fmaf(c3, bhi(pb1), m1);
    m0 = fmaf(c4, blo(pc0), m0); m1 = fmaf(c4, blo(pc1), m1);
    m0 = fmaf(c5, bhi(pc0), m0); m1 = fmaf(c5, bhi(pc1), m1);
    m0 = fmaf(c6, blo(pd0), m0); m1 = fmaf(c6, blo(pd1), m1);
    m0 = fmaf(c7, bhi(pd0), m0); m1 = fmaf(c7, bhi(pd1), m1);
    if (valid) { acc0 += m0; acc1 += m1; }
  }
  acc0 += __shfl_xor(acc0, 16, 64);
  acc0 += __shfl_xor(acc0, 32, 64);
  acc1 += __shfl_xor(acc1, 16, 64);
  acc1 += __shfl_xor(acc1, 32, 64);
}

// ---------- fused layer: 4-edge gather (4 waves x 4 nodes) -> hL -> MFMA ----------
__global__ __launch_bounds__(TPB, 4) void k_fused(
    const int* __restrict__ rowstart, const int* __restrict__ cnt,
    const float* __restrict__ icnt, const int* __restrict__ srcs,
    const float* __restrict__ kcs, const unsigned* __restrict__ Pbi,
    const float* __restrict__ Pri, const float* __restrict__ cbias,
    const uint4* __restrict__ Wb, unsigned* __restrict__ Pbo,
    float* __restrict__ Pro) {
  __shared__ float hL[512];
  const int tid = threadIdx.x, w = tid >> 6, lane = tid & 63;
  const int nb = blockIdx.x * 16;
  const int eq = lane >> 4, o16 = lane & 15;
#pragma unroll 1
  for (int q = 0; q < 4; q++) {
    int n = nb + 4 * w + q;
    int rs = rowstart[n], re = rs + cnt[n];
    float acc0, acc1;
    gather4(rs, re, eq, o16, srcs, kcs, Pbi, acc0, acc1);
    if (lane < 16) {
      float ic = icnt[n];
      int nq = 4 * w + q;
      hL[nq * 32 + o16] =
          fmaxf(fmaf(acc0, ic, Pri[(size_t)n * 32 + o16] + cbias[o16]), 0.f);
      hL[nq * 32 + 16 + o16] =
          fmaxf(fmaf(acc1, ic, Pri[(size_t)n * 32 + 16 + o16] + cbias[16 + o16]), 0.f);
    }
  }
  __syncthreads();
  // transform (R14/R15-proven): wave w owns kp=w + ct 16+w
  B8 Bf0, Bf1, Bf2, Bf3, Bf4;
  Bf0.q = Wb[(4 * w + 0) * 64 + lane];
  Bf1.q = Wb[(4 * w + 1) * 64 + lane];
  Bf2.q = Wb[(4 * w + 2) * 64 + lane];
  Bf3.q = Wb[(4 * w + 3) * 64 + lane];
  Bf4.q = Wb[(16 + w) * 64 + lane];
  const int row = lane & 15, k0 = (lane >> 4) * 8;
  B8 af;
#pragma unroll
  for (int ii = 0; ii < 8; ii++) af.u[ii] = f2b(hL[row * 32 + k0 + ii]);
  f32x4 z = {0.f, 0.f, 0.f, 0.f};
  f32x4 d0 = __builtin_amdgcn_mfma_f32_16x16x32_bf16(af.b, Bf0.b, z, 0, 0, 0);
  f32x4 d1 = __builtin_amdgcn_mfma_f32_16x16x32_bf16(af.b, Bf1.b, z, 0, 0, 0);
  f32x4 d2 = __builtin_amdgcn_mfma_f32_16x16x32_bf16(af.b, Bf2.b, z, 0, 0, 0);
  f32x4 d3 = __builtin_amdgcn_mfma_f32_16x16x32_bf16(af.b, Bf3.b, z, 0, 0, 0);
  f32x4 d4 = __builtin_amdgcn_mfma_f32_16x16x32_bf16(af.b, Bf4.b, z, 0, 0, 0);
  const int oo = lane & 15, r0 = (lane >> 4) * 4;
#pragma unroll
  for (int r = 0; r < 4; r++) {
    int n = nb + r0 + r;
    Pbo[(size_t)n * 160 + w * 32 + oo] = f2b(d0[r]) | ((unsigned)f2b(d2[r]) << 16);
    Pbo[(size_t)n * 160 + w * 32 + 16 + oo] = f2b(d1[r]) | ((unsigned)f2b(d3[r]) << 16);
    if (w == 0) Pbo[(size_t)n * 160 + 128 + oo] = f2b(d4[r]);
    else if (w == 1) Pbo[(size_t)n * 160 + 128 + 16 + oo] = f2b(d4[r]);
    else if (w == 2) Pro[(size_t)n * 32 + oo] = d4[r];
    else Pro[(size_t)n * 32 + 16 + oo] = d4[r];
  }
}

// ---------- final: 4-edge gather -> h -> fc2 -> out (1 wave/node) ----------
__global__ void k_final(const int* __restrict__ rowstart, const int* __restrict__ cnt,
                        const float* __restrict__ icnt, const int* __restrict__ srcs,
                        const float* __restrict__ kcs, const unsigned* __restrict__ Pb,
                        const float* __restrict__ Pr, const float* __restrict__ cbias,
                        const float* __restrict__ fc2w, const float* __restrict__ fc2b,
                        float* __restrict__ out) {
  int t = blockIdx.x * TPB + threadIdx.x;
  int n = t >> 6;
  if (n >= NN) return;
  int lane = threadIdx.x & 63;
  int eq = lane >> 4, o16 = lane & 15;
  int rs = rowstart[n], re = rs + cnt[n];
  float acc0, acc1;
  gather4(rs, re, eq, o16, srcs, kcs, Pb, acc0, acc1);
  float ic = icnt[n];
  float hv0 = fmaxf(fmaf(acc0, ic, Pr[(size_t)n * 32 + o16] + cbias[o16]), 0.f);
  float hv1 = fmaxf(fmaf(acc1, ic, Pr[(size_t)n * 32 + 16 + o16] + cbias[16 + o16]), 0.f);
  float s2 = fmaf(hv0, fc2w[o16], hv1 * fc2w[16 + o16]);
#pragma unroll
  for (int d = 8; d; d >>= 1) s2 += __shfl_xor(s2, d, 16);
  if (lane == 0) out[n] = s2 + fc2b[0];
}

extern "C" void kernel_launch(void* const* d_in, const int* in_sizes, int n_in,
                              void* d_out, int out_size, void* d_ws, size_t ws_size,
                              hipStream_t stream) {
  const float* x     = (const float*)d_in[0];
  const int*   ei    = (const int*)d_in[1];
  const float* ea    = (const float*)d_in[2];
  const float* fc1w  = (const float*)d_in[3];
  const float* fc1b  = (const float*)d_in[4];
  const float* kw1   = (const float*)d_in[5];
  const float* kb1   = (const float*)d_in[6];
  const float* kw2   = (const float*)d_in[7];
  const float* kb2   = (const float*)d_in[8];
  const float* root  = (const float*)d_in[9];
  const float* cbias = (const float*)d_in[10];
  const float* fc2w  = (const float*)d_in[11];
  const float* fc2b  = (const float*)d_in[12];
  float* out = (float*)d_out;
  const int* srcp = ei;
  const int* dstp = ei + NE;

  float* ws = (float*)d_ws;
  float* kc       = ws;                        // NE*8
  float* kcs      = kc + NE * 8;               // NE*8
  int*   srcs     = (int*)(kcs + NE * 8);      // NE
  float* icnt     = (float*)(srcs + NE);       // NN
  float* Pr0      = icnt + NN;                 // NN*32
  float* Pr1      = Pr0 + NN * 32;             // NN*32
  int*   cnt      = (int*)(Pr1 + NN * 32);     // NN
  int*   rowstart = cnt + NN;                  // NN
  int*   wpos     = rowstart + NN;             // NN
  int*   gtotal   = wpos + NN;                 // 1 (+pad)
  uint4* Wb       = (uint4*)(gtotal + 128);    // 1280 uint4
  unsigned* Pb0   = (unsigned*)(Wb + 1280);    // NN*160
  unsigned* Pb1   = Pb0 + (size_t)NN * 160;    // NN*160

  k_init<<<SB + 5, TPB, 0, stream>>>(cnt, gtotal, kw2, kb2, root, Wb);
  k_prep<<<(NE + TPB - 1) / TPB, TPB, 0, stream>>>(ea, kw1, kb1, dstp, kc, cnt);
  k_alloc<<<SB, TPB, 0, stream>>>(cnt, gtotal, rowstart, wpos, icnt);
  k_scatnode<<<NB1 + NB1, TPB, 0, stream>>>(dstp, srcp, kc, wpos, srcs, kcs,
                                            x, fc1w, fc1b, Wb, Pb0, Pr0);
  k_fused<<<NW, TPB, 0, stream>>>(rowstart, cnt, icnt, srcs, kcs, Pb0, Pr0, cbias,
                                  Wb, Pb1, Pr1);
  k_fused<<<NW, TPB, 0, stream>>>(rowstart, cnt, icnt, srcs, kcs, Pb1, Pr1, cbias,
                                  Wb, Pb0, Pr0);
  k_fused<<<NW, TPB, 0, stream>>>(rowstart, cnt, icnt, srcs, kcs, Pb0, Pr0, cbias,
                                  Wb, Pb1, Pr1);
  k_final<<<(NN * 64 + TPB - 1) / TPB, TPB, 0, stream>>>(
      rowstart, cnt, icnt, srcs, kcs, Pb1, Pr1, cbias, fc2w, fc2b, out);
}